// Round 23
// baseline (1861.349 us; speedup 1.0000x reference)
//
#include <hip/hip_runtime.h>
#include <hip/hip_bf16.h>
#include <stdint.h>

#define BB 32
#define NN 128
#define TT 16
#define FN 16
#define FE 8
#define FG 8
#define FH 16
#define HH 128
#define DEC 64

// ws layout (floats):
// base_node @0        [524288]
// We        @524288   [1024]
// mg        @525312   [4096]
// eg16      @529408   [2097152]
// jl (int)  @2626560  [524288]
// cnt (int) @3150848  [4096]
// WhW       @3154944  [6144]
// baseW     @3161088  [1572864]
// m1p       @4733952  [524288]
// m2        @5258240  [524288]
// o1        @5782528  [524288]
// hid       @6306816  [524288]
// Wj        @6831104  [49152]     ([32 kk][3 m][128 h][4 u])
// zfull     @6880256  [25165824]  ([16 t][3 m][4096 row][128 h])
// Wo2j      @32046080 [16384]
// Wdnj      @32062464 [8192]
// Wdej      @32070656 [8192]
// end 32078848 floats = 128.3 MB (ws = 256 MB)

__global__ __launch_bounds__(HH) void prep1(const float* __restrict__ node,
                                            const float* __restrict__ Wn,
                                            float* __restrict__ base_node) {
    int row = blockIdx.x;
    int h = threadIdx.x;
    float acc = 0.f;
#pragma unroll
    for (int f = 0; f < FN; ++f)
        acc += node[row * FN + f] * Wn[f * HH + h];
    base_node[row * HH + h] = acc;
}

__global__ __launch_bounds__(HH) void prep2(const float* __restrict__ graph,
                                            const float* __restrict__ Wg,
                                            const float* __restrict__ Wmg,
                                            const float* __restrict__ Wee,
                                            const float* __restrict__ Wme,
                                            float* __restrict__ mg,
                                            float* __restrict__ We) {
    int h = threadIdx.x;
    if (blockIdx.x < BB) {
        int b = blockIdx.x;
        __shared__ float gf[HH];
        float acc = 0.f;
#pragma unroll
        for (int f = 0; f < FG; ++f) acc += graph[b * FG + f] * Wg[f * HH + h];
        gf[h] = acc;
        __syncthreads();
        float a2 = 0.f;
#pragma unroll 16
        for (int k = 0; k < HH; ++k) a2 += gf[k] * Wmg[k * HH + h];
        mg[b * HH + h] = a2;
    } else {
        int f = blockIdx.x - BB;
        float acc = 0.f;
#pragma unroll 16
        for (int k = 0; k < HH; ++k) acc += Wee[f * HH + k] * Wme[k * HH + h];
        We[f * HH + h] = acc;
    }
}

__device__ __forceinline__ uint32_t bf16rne(float v) {
    uint32_t b = __float_as_uint(v);
    return (b + 0x7fffu + ((b >> 16) & 1u)) >> 16;
}

__global__ __launch_bounds__(HH) void prep3(const float* __restrict__ edge,
                                            const int* __restrict__ adj,
                                            uint4* __restrict__ eg16,
                                            int* __restrict__ jl,
                                            int* __restrict__ cnt) {
    int bi = blockIdx.x;
    int j = threadIdx.x;
    __shared__ int w0cnt, totc, j0s;
    bool valid = adj[(size_t)bi * NN + j] > 0;
    unsigned long long mask = __ballot(valid);
    int lane = j & 63;
    int wave = j >> 6;
    int prefix = __popcll(mask & ((1ull << lane) - 1ull));
    int wcount = __popcll(mask);
    if (wave == 0 && lane == 0) w0cnt = wcount;
    __syncthreads();
    int base = (wave == 1) ? w0cnt : 0;
    if (wave == 1 && lane == 0) totc = w0cnt + wcount;
    int pos = base + prefix;
    if (valid && pos == 0) j0s = j;
    __syncthreads();
    int c = totc;
    int cpad = (c + 7) & ~7;
    if (j == 0) cnt[bi] = cpad;

    if (valid) {
        jl[bi * NN + pos] = j;
        const float* src = edge + ((size_t)bi * NN + j) * FE;
        uint4 r;
        r.x = bf16rne(src[0]) | (bf16rne(src[1]) << 16);
        r.y = bf16rne(src[2]) | (bf16rne(src[3]) << 16);
        r.z = bf16rne(src[4]) | (bf16rne(src[5]) << 16);
        r.w = bf16rne(src[6]) | (bf16rne(src[7]) << 16);
        eg16[(size_t)bi * NN + pos] = r;
    }
    if (c > 0 && j >= c && j < cpad) {
        int j0 = j0s;
        jl[bi * NN + j] = j0;
        const float* src = edge + ((size_t)bi * NN + j0) * FE;
        uint4 r;
        r.x = bf16rne(src[0]) | (bf16rne(src[1]) << 16);
        r.y = bf16rne(src[2]) | (bf16rne(src[3]) << 16);
        r.z = bf16rne(src[4]) | (bf16rne(src[5]) << 16);
        r.w = bf16rne(src[6]) | (bf16rne(src[7]) << 16);
        eg16[(size_t)bi * NN + j] = r;
    }
}

// WhW[m][f][h] = sum_k Wh[f][k] * Wm[k][h]
__global__ __launch_bounds__(HH) void prepW(
    const float* __restrict__ Wh, const float* __restrict__ Wm1,
    const float* __restrict__ Wm2, const float* __restrict__ Wo1,
    float* __restrict__ WhW) {
    const int h = threadIdx.x;
    const int m = blockIdx.x >> 4;
    const int f = blockIdx.x & 15;
    const float* __restrict__ W = (m == 0) ? Wm1 : (m == 1) ? Wm2 : Wo1;
    float acc = 0.f;
#pragma unroll 16
    for (int k = 0; k < HH; ++k)
        acc = fmaf(Wh[f * HH + k], W[k * HH + h], acc);
    WhW[(m * FH + f) * HH + h] = acc;
}

// Wj[((kk*3 + m)*128 + h)*4 + u] = Wm[(128 + kk*4 + u)*128 + h]
__global__ __launch_bounds__(256) void prepJ(
    const float* __restrict__ Wm1, const float* __restrict__ Wm2,
    const float* __restrict__ Wo1, float* __restrict__ Wj) {
    int idx = blockIdx.x * 256 + threadIdx.x;
    int kk = idx / 1536;
    int rem = idx - kk * 1536;
    int m = rem >> 9;
    int r2 = rem & 511;
    int h = r2 >> 2;
    int u = r2 & 3;
    const float* __restrict__ W = (m == 0) ? Wm1 : (m == 1) ? Wm2 : Wo1;
    Wj[idx] = W[(HH + kk * 4 + u) * HH + h];
}

// Interleave Wo2 / Wdn / Wde for b128 reads.
__global__ __launch_bounds__(256) void prepO(
    const float* __restrict__ Wo2, const float* __restrict__ Wdn,
    const float* __restrict__ Wde, float* __restrict__ Wo2j,
    float* __restrict__ Wdnj, float* __restrict__ Wdej) {
    int idx = blockIdx.x * 256 + threadIdx.x;   // 0..32767
    if (idx < 16384) {
        int kk = idx >> 9;
        int h = (idx >> 2) & 127;
        int u = idx & 3;
        Wo2j[idx] = Wo2[(kk * 4 + u) * HH + h];
    } else {
        int i2 = idx - 16384;
        int which = i2 >> 13;
        int j2 = i2 & 8191;
        int kk = j2 >> 8;
        int hh = (j2 >> 2) & 63;
        int u = j2 & 3;
        if (which == 0)
            Wdnj[j2] = Wdn[(kk * 4 + u) * DEC + hh];
        else
            Wdej[j2] = Wde[(kk * 4 + u) * DEC + hh];
    }
}

// baseW[m][row][h] = base_node[row] @ Wm[:128] (+mg for m=0)
__global__ __launch_bounds__(512, 4) void prepB(
    const float* __restrict__ base_node,
    const float* __restrict__ Wm1, const float* __restrict__ Wm2,
    const float* __restrict__ Wo1, const float* __restrict__ mg,
    float* __restrict__ baseW) {
    __shared__ float zs[8][HH];
    const int tid = threadIdx.x;
    const int lane = tid & 127;
    const int grp = tid >> 7;
    const int bid = blockIdx.x;
    const int tile = (bid & 7) * 64 + (bid >> 3);
    const int row0 = tile * 8;
    const int rg0 = grp * 2, rg1 = rg0 + 1;

    zs[rg0][lane] = base_node[(size_t)(row0 + rg0) * HH + lane];
    zs[rg1][lane] = base_node[(size_t)(row0 + rg1) * HH + lane];
    __syncthreads();

    float acc[2][3];
#pragma unroll
    for (int e = 0; e < 2; ++e) { acc[e][0] = 0.f; acc[e][1] = 0.f; acc[e][2] = 0.f; }

#pragma unroll 4
    for (int kk = 0; kk < 32; ++kk) {
        const int k0 = kk * 4;
        float4 z0 = *(const float4*)&zs[rg0][k0];
        float4 z1 = *(const float4*)&zs[rg1][k0];
#define PBU(COMP, KO)                                                   \
        {                                                               \
            const float w1 = Wm1[(k0 + KO) * HH + lane];                \
            const float w2 = Wm2[(k0 + KO) * HH + lane];                \
            const float w3 = Wo1[(k0 + KO) * HH + lane];                \
            acc[0][0] = fmaf(z0.COMP, w1, acc[0][0]);                   \
            acc[1][0] = fmaf(z1.COMP, w1, acc[1][0]);                   \
            acc[0][1] = fmaf(z0.COMP, w2, acc[0][1]);                   \
            acc[1][1] = fmaf(z1.COMP, w2, acc[1][1]);                   \
            acc[0][2] = fmaf(z0.COMP, w3, acc[0][2]);                   \
            acc[1][2] = fmaf(z1.COMP, w3, acc[1][2]);                   \
        }
        PBU(x, 0) PBU(y, 1) PBU(z, 2) PBU(w, 3)
#undef PBU
    }

#pragma unroll
    for (int e = 0; e < 2; ++e) {
        const int row = row0 + grp * 2 + e;
        const float mgv = mg[(row >> 7) * HH + lane];
        baseW[((size_t)0 * 4096 + row) * HH + lane] = acc[e][0] + mgv;
        baseW[((size_t)1 * 4096 + row) * HH + lane] = acc[e][1];
        baseW[((size_t)2 * 4096 + row) * HH + lane] = acc[e][2];
    }
}

// prepH (exact R18 version): 8192 blocks (16 t x 512 tiles) x 256 thr.
__global__ __launch_bounds__(256) void prepH(
    const float* __restrict__ baseW, const float* __restrict__ WhW,
    const float* __restrict__ hints, float* __restrict__ zfull) {
    const int tid = threadIdx.x;
    const int lane = tid & 127;
    const int grp = tid >> 7;
    const int bid = blockIdx.x;
    const int t = bid >> 9;
    const int bl = bid & 511;
    const int tile = (bl & 7) * 64 + (bl >> 3);
    const int row0 = tile * 8 + grp * 4;
    const size_t zo = (size_t)t * 3 * 4096 * HH;

#pragma unroll
    for (int e = 0; e < 4; ++e) {
        const int row = row0 + e;
        float s0 = baseW[((size_t)0 * 4096 + row) * HH + lane];
        float s1 = baseW[((size_t)1 * 4096 + row) * HH + lane];
        float s2 = baseW[((size_t)2 * 4096 + row) * HH + lane];
        if (t > 0) {
            const float* __restrict__ hr =
                hints + ((size_t)(t - 1) * BB * NN + row) * FH;
#pragma unroll
            for (int f = 0; f < FH; ++f) {
                const float hf = hr[f];
                s0 = fmaf(hf, WhW[(0 * FH + f) * HH + lane], s0);
                s1 = fmaf(hf, WhW[(1 * FH + f) * HH + lane], s1);
                s2 = fmaf(hf, WhW[(2 * FH + f) * HH + lane], s2);
            }
        }
        zfull[zo + ((size_t)0 * 4096 + row) * HH + lane] = s0;
        zfull[zo + ((size_t)1 * 4096 + row) * HH + lane] = s1;
        zfull[zo + ((size_t)2 * 4096 + row) * HH + lane] = s2;
    }
}

// K1 (exact R18 version): 512 blocks x 256 thr, Wj b128 coalesced weights.
__global__ __launch_bounds__(256) void k1_gemm(
    const float* __restrict__ hid, const float* __restrict__ Wj,
    const float* __restrict__ zp,
    float* __restrict__ m1n, float* __restrict__ m2n, float* __restrict__ o1n) {
    __shared__ float zs[8][HH];
    const int tid = threadIdx.x;
    const int lane = tid & 127;
    const int grp = tid >> 7;
    const int g4 = grp * 4;
    const int bid = blockIdx.x;
    const int tile = (bid & 7) * 64 + (bid >> 3);
    const int row0 = tile * 8;

#pragma unroll
    for (int rr = 0; rr < 4; ++rr)
        zs[g4 + rr][lane] = hid[(size_t)(row0 + g4 + rr) * HH + lane];
    __syncthreads();

    float acc[4][3];
#pragma unroll
    for (int r = 0; r < 4; ++r) { acc[r][0] = 0.f; acc[r][1] = 0.f; acc[r][2] = 0.f; }

#pragma unroll 2
    for (int kk = 0; kk < 32; ++kk) {
        const float* __restrict__ wb = Wj + (size_t)kk * 1536 + lane * 4;
        float4 w1 = *(const float4*)(wb);
        float4 w2 = *(const float4*)(wb + 512);
        float4 w3 = *(const float4*)(wb + 1024);
        float4 z0 = *(const float4*)&zs[g4 + 0][kk * 4];
        float4 z1 = *(const float4*)&zs[g4 + 1][kk * 4];
        float4 z2 = *(const float4*)&zs[g4 + 2][kk * 4];
        float4 z3 = *(const float4*)&zs[g4 + 3][kk * 4];
#define K1R(ZR, R)                                                      \
        acc[R][0] = fmaf(ZR.x, w1.x, acc[R][0]);                        \
        acc[R][0] = fmaf(ZR.y, w1.y, acc[R][0]);                        \
        acc[R][0] = fmaf(ZR.z, w1.z, acc[R][0]);                        \
        acc[R][0] = fmaf(ZR.w, w1.w, acc[R][0]);                        \
        acc[R][1] = fmaf(ZR.x, w2.x, acc[R][1]);                        \
        acc[R][1] = fmaf(ZR.y, w2.y, acc[R][1]);                        \
        acc[R][1] = fmaf(ZR.z, w2.z, acc[R][1]);                        \
        acc[R][1] = fmaf(ZR.w, w2.w, acc[R][1]);                        \
        acc[R][2] = fmaf(ZR.x, w3.x, acc[R][2]);                        \
        acc[R][2] = fmaf(ZR.y, w3.y, acc[R][2]);                        \
        acc[R][2] = fmaf(ZR.z, w3.z, acc[R][2]);                        \
        acc[R][2] = fmaf(ZR.w, w3.w, acc[R][2]);
        K1R(z0, 0) K1R(z1, 1) K1R(z2, 2) K1R(z3, 3)
#undef K1R
    }

#pragma unroll
    for (int e = 0; e < 4; ++e) {
        const int row = row0 + g4 + e;
        m1n[(size_t)row * HH + lane] =
            acc[e][0] + zp[((size_t)0 * 4096 + row) * HH + lane];
        m2n[(size_t)row * HH + lane] =
            acc[e][1] + zp[((size_t)1 * 4096 + row) * HH + lane];
        o1n[(size_t)row * HH + lane] =
            acc[e][2] + zp[((size_t)2 * 4096 + row) * HH + lane];
    }
}

// K2 (R18 geometry) + LDS-staged eg/jl tables: chunk loop's VMEM queue
// contains only the m2 gathers. Bitwise-identical FMA order.
__global__ __launch_bounds__(HH) void k2_max(
    const uint4* __restrict__ eg16, const int* __restrict__ jl,
    const int* __restrict__ cnt, const float* __restrict__ We,
    const float* __restrict__ m1p, const float* __restrict__ m2,
    const float* __restrict__ o1, const float* __restrict__ Wo2j,
    const float* __restrict__ Wdnj, const float* __restrict__ Wdej,
    float* __restrict__ hid, float* __restrict__ out, int t, int last) {
    __shared__ float agg_lds[HH];
    __shared__ float hnew_lds[HH];
    __shared__ uint4 eg_lds[NN];
    __shared__ int jl_lds[NN];
    const int h = threadIdx.x;
    const int bid = blockIdx.x;
    const int bi = (bid & 7) * 512 + (bid >> 3);
    const int b = bi >> 7;

    // stage full eg row + jl row (1 b128 + 1 b32 per thread)
    eg_lds[h] = eg16[(size_t)bi * NN + h];
    jl_lds[h] = jl[bi * NN + h];

    const float we0 = We[0 * HH + h], we1 = We[1 * HH + h];
    const float we2 = We[2 * HH + h], we3 = We[3 * HH + h];
    const float we4 = We[4 * HH + h], we5 = We[5 * HH + h];
    const float we6 = We[6 * HH + h], we7 = We[7 * HH + h];

    const float* __restrict__ m2b = m2 + (size_t)b * NN * HH;
    const int cp = cnt[bi];
    const float m1v = m1p[(size_t)bi * HH + h];
    const float o1v = o1[(size_t)bi * HH + h];
    __syncthreads();

    float M = -3e38f;
    const int nch = cp >> 3;
    for (int ch = 0; ch < nch; ++ch) {
        const int k0 = ch * 8;
        uint4 raw[8];
        int jj[8];
        float mv[8];
#pragma unroll
        for (int s = 0; s < 8; ++s) jj[s] = jl_lds[k0 + s];
#pragma unroll
        for (int s = 0; s < 8; ++s) raw[s] = eg_lds[k0 + s];
#pragma unroll
        for (int s = 0; s < 8; ++s) mv[s] = m2b[jj[s] * HH + h];
#pragma unroll
        for (int s = 0; s < 8; ++s) {
            uint32_t x = raw[s].x, y = raw[s].y, z = raw[s].z, w = raw[s].w;
            float e = __uint_as_float(x << 16) * we0;
            e = fmaf(__uint_as_float(x & 0xffff0000u), we1, e);
            e = fmaf(__uint_as_float(y << 16), we2, e);
            e = fmaf(__uint_as_float(y & 0xffff0000u), we3, e);
            e = fmaf(__uint_as_float(z << 16), we4, e);
            e = fmaf(__uint_as_float(z & 0xffff0000u), we5, e);
            e = fmaf(__uint_as_float(w << 16), we6, e);
            e = fmaf(__uint_as_float(w & 0xffff0000u), we7, e);
            M = fmaxf(M, e + mv[s]);
        }
    }
    float agg = (cp > 0) ? fmaxf(m1v + M, 0.f) : -1e9f;
    agg_lds[h] = agg;
    __syncthreads();

    float acc = o1v;
    const float4* a4 = (const float4*)agg_lds;
#pragma unroll 8
    for (int kk = 0; kk < 32; ++kk) {
        float4 a = a4[kk];
        float4 w = *(const float4*)&Wo2j[(kk * HH + h) * 4];
        acc = fmaf(a.x, w.x, acc);
        acc = fmaf(a.y, w.y, acc);
        acc = fmaf(a.z, w.z, acc);
        acc = fmaf(a.w, w.w, acc);
    }
    float hv = fmaxf(acc, 0.f);
    hid[(size_t)bi * HH + h] = hv;

    if (last) {
        hnew_lds[h] = hv;
        __syncthreads();
        if (h < DEC) {
            float a = 0.f, e2 = 0.f;
            const float4* h4p = (const float4*)hnew_lds;
#pragma unroll 8
            for (int kk = 0; kk < 32; ++kk) {
                float4 hv4 = h4p[kk];
                float4 av4 = a4[kk];
                float4 wn = *(const float4*)&Wdnj[(kk * DEC + h) * 4];
                float4 wd = *(const float4*)&Wdej[(kk * DEC + h) * 4];
                a = fmaf(hv4.x, wn.x, a);
                a = fmaf(hv4.y, wn.y, a);
                a = fmaf(hv4.z, wn.z, a);
                a = fmaf(hv4.w, wn.w, a);
                e2 = fmaf(av4.x, wd.x, e2);
                e2 = fmaf(av4.y, wd.y, e2);
                e2 = fmaf(av4.z, wd.z, e2);
                e2 = fmaf(av4.w, wd.w, e2);
            }
            out[(((size_t)t * BB + b) * NN + (bi & 127)) * DEC + h] = a + e2;
        }
    }
}

extern "C" void kernel_launch(void* const* d_in, const int* in_sizes, int n_in,
                              void* d_out, int out_size, void* d_ws, size_t ws_size,
                              hipStream_t stream) {
    const float* node = (const float*)d_in[0];
    const float* edge = (const float*)d_in[1];
    const float* graph = (const float*)d_in[2];
    const float* hints = (const float*)d_in[3];
    const int* adj = (const int*)d_in[4];
    const float* Wn = (const float*)d_in[5];
    const float* Wh = (const float*)d_in[6];
    const float* Wee = (const float*)d_in[7];
    const float* Wg = (const float*)d_in[8];
    const float* Wm1 = (const float*)d_in[9];
    const float* Wm2 = (const float*)d_in[10];
    const float* Wme = (const float*)d_in[11];
    const float* Wmg = (const float*)d_in[12];
    const float* Wo1 = (const float*)d_in[13];
    const float* Wo2 = (const float*)d_in[14];
    const float* Wdn = (const float*)d_in[15];
    const float* Wde = (const float*)d_in[16];

    float* ws = (float*)d_ws;
    float* base_node = ws;
    float* We = ws + 524288;
    float* mg = ws + 525312;
    uint4* eg16 = (uint4*)(ws + 529408);
    int* jl = (int*)(ws + 2626560);
    int* cnt = (int*)(ws + 3150848);
    float* WhW = ws + 3154944;
    float* baseW = ws + 3161088;
    float* m1p = ws + 4733952;
    float* m2 = ws + 5258240;
    float* o1 = ws + 5782528;
    float* hid = ws + 6306816;
    float* Wj = ws + 6831104;
    float* zfull = ws + 6880256;
    float* Wo2j = ws + 32046080;
    float* Wdnj = ws + 32062464;
    float* Wdej = ws + 32070656;
    float* out = (float*)d_out;

    const size_t MS = (size_t)4096 * HH;

    prep1<<<BB * NN, HH, 0, stream>>>(node, Wn, base_node);
    prep2<<<BB + FE, HH, 0, stream>>>(graph, Wg, Wmg, Wee, Wme, mg, We);
    prep3<<<BB * NN, HH, 0, stream>>>(edge, adj, eg16, jl, cnt);
    prepW<<<48, HH, 0, stream>>>(Wh, Wm1, Wm2, Wo1, WhW);
    prepJ<<<192, 256, 0, stream>>>(Wm1, Wm2, Wo1, Wj);
    prepO<<<128, 256, 0, stream>>>(Wo2, Wdn, Wde, Wo2j, Wdnj, Wdej);
    prepB<<<512, 512, 0, stream>>>(base_node, Wm1, Wm2, Wo1, mg, baseW);
    prepH<<<8192, 256, 0, stream>>>(baseW, WhW, hints, zfull);

    for (int r = 0; r < 48; ++r) {
        const int t = r / 3;
        const int last = ((r % 3) == 2) ? 1 : 0;
        const float* zt = zfull + (size_t)t * 3 * MS;
        const float *m1c, *m2c, *o1c;
        if (r == 0) {
            m1c = zt; m2c = zt + MS; o1c = zt + 2 * MS;
        } else {
            k1_gemm<<<512, 256, 0, stream>>>(hid, Wj, zt, m1p, m2, o1);
            m1c = m1p; m2c = m2; o1c = o1;
        }
        k2_max<<<BB * NN, HH, 0, stream>>>(eg16, jl, cnt, We, m1c, m2c, o1c,
                                           Wo2j, Wdnj, Wdej, hid, out, t, last);
    }
}

// Round 24
// 1801.887 us; speedup vs baseline: 1.0330x; 1.0330x over previous
//
#include <hip/hip_runtime.h>
#include <hip/hip_bf16.h>
#include <stdint.h>

#define BB 32
#define NN 128
#define TT 16
#define FN 16
#define FE 8
#define FG 8
#define FH 16
#define HH 128
#define DEC 64

// ws layout (floats):
// We        @524288   [1024]
// mg        @525312   [4096]
// eg16      @529408   [2097152]
// jl (int)  @2626560  [524288]
// cnt (int) @3150848  [4096]
// WhW       @3154944  [6144]
// baseW     @3161088  [1572864]   ([3][4096][128], m1 slice includes +mg)
// m1p       @4733952  [524288]
// m2        @5258240  [524288]
// o1        @5782528  [524288]
// hid       @6306816  [524288]
// Wj        @6831104  [49152]     ([32 kk][3 m][128 h][4 u])
// zfull     @6880256  [23592960]  ([15 t (t=1..15)][3 m][4096 row][128 h])
// Wo2j      @32046080 [16384]
// Wdnj      @32062464 [8192]
// Wdej      @32070656 [8192]
// end 32078848 floats = 128.3 MB (ws = 256 MB)

__global__ __launch_bounds__(HH) void prep2(const float* __restrict__ graph,
                                            const float* __restrict__ Wg,
                                            const float* __restrict__ Wmg,
                                            const float* __restrict__ Wee,
                                            const float* __restrict__ Wme,
                                            float* __restrict__ mg,
                                            float* __restrict__ We) {
    int h = threadIdx.x;
    if (blockIdx.x < BB) {
        int b = blockIdx.x;
        __shared__ float gf[HH];
        float acc = 0.f;
#pragma unroll
        for (int f = 0; f < FG; ++f) acc += graph[b * FG + f] * Wg[f * HH + h];
        gf[h] = acc;
        __syncthreads();
        float a2 = 0.f;
#pragma unroll 16
        for (int k = 0; k < HH; ++k) a2 += gf[k] * Wmg[k * HH + h];
        mg[b * HH + h] = a2;
    } else {
        int f = blockIdx.x - BB;
        float acc = 0.f;
#pragma unroll 16
        for (int k = 0; k < HH; ++k) acc += Wee[f * HH + k] * Wme[k * HH + h];
        We[f * HH + h] = acc;
    }
}

__device__ __forceinline__ uint32_t bf16rne(float v) {
    uint32_t b = __float_as_uint(v);
    return (b + 0x7fffu + ((b >> 16) & 1u)) >> 16;
}

__global__ __launch_bounds__(HH) void prep3(const float* __restrict__ edge,
                                            const int* __restrict__ adj,
                                            uint4* __restrict__ eg16,
                                            int* __restrict__ jl,
                                            int* __restrict__ cnt) {
    int bi = blockIdx.x;
    int j = threadIdx.x;
    __shared__ int w0cnt, totc, j0s;
    bool valid = adj[(size_t)bi * NN + j] > 0;
    unsigned long long mask = __ballot(valid);
    int lane = j & 63;
    int wave = j >> 6;
    int prefix = __popcll(mask & ((1ull << lane) - 1ull));
    int wcount = __popcll(mask);
    if (wave == 0 && lane == 0) w0cnt = wcount;
    __syncthreads();
    int base = (wave == 1) ? w0cnt : 0;
    if (wave == 1 && lane == 0) totc = w0cnt + wcount;
    int pos = base + prefix;
    if (valid && pos == 0) j0s = j;
    __syncthreads();
    int c = totc;
    int cpad = (c + 7) & ~7;
    if (j == 0) cnt[bi] = cpad;

    if (valid) {
        jl[bi * NN + pos] = j;
        const float* src = edge + ((size_t)bi * NN + j) * FE;
        uint4 r;
        r.x = bf16rne(src[0]) | (bf16rne(src[1]) << 16);
        r.y = bf16rne(src[2]) | (bf16rne(src[3]) << 16);
        r.z = bf16rne(src[4]) | (bf16rne(src[5]) << 16);
        r.w = bf16rne(src[6]) | (bf16rne(src[7]) << 16);
        eg16[(size_t)bi * NN + pos] = r;
    }
    if (c > 0 && j >= c && j < cpad) {
        int j0 = j0s;
        jl[bi * NN + j] = j0;
        const float* src = edge + ((size_t)bi * NN + j0) * FE;
        uint4 r;
        r.x = bf16rne(src[0]) | (bf16rne(src[1]) << 16);
        r.y = bf16rne(src[2]) | (bf16rne(src[3]) << 16);
        r.z = bf16rne(src[4]) | (bf16rne(src[5]) << 16);
        r.w = bf16rne(src[6]) | (bf16rne(src[7]) << 16);
        eg16[(size_t)bi * NN + j] = r;
    }
}

// Merged prepW + prepJ + prepO. Grid = 368 blocks x 256 thr.
// bid 0..47: WhW (tid<128).  bid 48..239: Wj.  bid 240..367: Wo2j/Wdnj/Wdej.
__global__ __launch_bounds__(256) void prepWJO(
    const float* __restrict__ Wh, const float* __restrict__ Wm1,
    const float* __restrict__ Wm2, const float* __restrict__ Wo1,
    const float* __restrict__ Wo2, const float* __restrict__ Wdn,
    const float* __restrict__ Wde,
    float* __restrict__ WhW, float* __restrict__ Wj,
    float* __restrict__ Wo2j, float* __restrict__ Wdnj,
    float* __restrict__ Wdej) {
    const int bid = blockIdx.x;
    const int tid = threadIdx.x;
    if (bid < 48) {
        if (tid < HH) {
            const int h = tid;
            const int m = bid >> 4;
            const int f = bid & 15;
            const float* __restrict__ W = (m == 0) ? Wm1 : (m == 1) ? Wm2 : Wo1;
            float acc = 0.f;
#pragma unroll 16
            for (int k = 0; k < HH; ++k)
                acc = fmaf(Wh[f * HH + k], W[k * HH + h], acc);
            WhW[(m * FH + f) * HH + h] = acc;
        }
    } else if (bid < 240) {
        int idx = (bid - 48) * 256 + tid;   // 0..49151
        int kk = idx / 1536;
        int rem = idx - kk * 1536;
        int m = rem >> 9;
        int r2 = rem & 511;
        int h = r2 >> 2;
        int u = r2 & 3;
        const float* __restrict__ W = (m == 0) ? Wm1 : (m == 1) ? Wm2 : Wo1;
        Wj[idx] = W[(HH + kk * 4 + u) * HH + h];
    } else {
        int idx = (bid - 240) * 256 + tid;  // 0..32767
        if (idx < 16384) {
            int kk = idx >> 9;
            int h = (idx >> 2) & 127;
            int u = idx & 3;
            Wo2j[idx] = Wo2[(kk * 4 + u) * HH + h];
        } else {
            int i2 = idx - 16384;
            int which = i2 >> 13;
            int j2 = i2 & 8191;
            int kk = j2 >> 8;
            int hh = (j2 >> 2) & 63;
            int u = j2 & 3;
            if (which == 0)
                Wdnj[j2] = Wdn[(kk * 4 + u) * DEC + hh];
            else
                Wdej[j2] = Wde[(kk * 4 + u) * DEC + hh];
        }
    }
}

// baseW[m][row][h] = (node[row] @ Wn) @ Wm[:128] (+mg for m=0).
// Node encoder folded into staging (identical FMA order to the old prep1).
__global__ __launch_bounds__(512, 4) void prepB(
    const float* __restrict__ node, const float* __restrict__ Wn,
    const float* __restrict__ Wm1, const float* __restrict__ Wm2,
    const float* __restrict__ Wo1, const float* __restrict__ mg,
    float* __restrict__ baseW) {
    __shared__ float zs[8][HH];
    const int tid = threadIdx.x;
    const int lane = tid & 127;
    const int grp = tid >> 7;
    const int bid = blockIdx.x;
    const int tile = (bid & 7) * 64 + (bid >> 3);
    const int row0 = tile * 8;
    const int rg0 = grp * 2, rg1 = rg0 + 1;

    {
        float a0 = 0.f, a1 = 0.f;
        const float* __restrict__ n0 = node + (size_t)(row0 + rg0) * FN;
        const float* __restrict__ n1 = node + (size_t)(row0 + rg1) * FN;
#pragma unroll
        for (int f = 0; f < FN; ++f) {
            const float w = Wn[f * HH + lane];
            a0 += n0[f] * w;
            a1 += n1[f] * w;
        }
        zs[rg0][lane] = a0;
        zs[rg1][lane] = a1;
    }
    __syncthreads();

    float acc[2][3];
#pragma unroll
    for (int e = 0; e < 2; ++e) { acc[e][0] = 0.f; acc[e][1] = 0.f; acc[e][2] = 0.f; }

#pragma unroll 4
    for (int kk = 0; kk < 32; ++kk) {
        const int k0 = kk * 4;
        float4 z0 = *(const float4*)&zs[rg0][k0];
        float4 z1 = *(const float4*)&zs[rg1][k0];
#define PBU(COMP, KO)                                                   \
        {                                                               \
            const float w1 = Wm1[(k0 + KO) * HH + lane];                \
            const float w2 = Wm2[(k0 + KO) * HH + lane];                \
            const float w3 = Wo1[(k0 + KO) * HH + lane];                \
            acc[0][0] = fmaf(z0.COMP, w1, acc[0][0]);                   \
            acc[1][0] = fmaf(z1.COMP, w1, acc[1][0]);                   \
            acc[0][1] = fmaf(z0.COMP, w2, acc[0][1]);                   \
            acc[1][1] = fmaf(z1.COMP, w2, acc[1][1]);                   \
            acc[0][2] = fmaf(z0.COMP, w3, acc[0][2]);                   \
            acc[1][2] = fmaf(z1.COMP, w3, acc[1][2]);                   \
        }
        PBU(x, 0) PBU(y, 1) PBU(z, 2) PBU(w, 3)
#undef PBU
    }

#pragma unroll
    for (int e = 0; e < 2; ++e) {
        const int row = row0 + grp * 2 + e;
        const float mgv = mg[(row >> 7) * HH + lane];
        baseW[((size_t)0 * 4096 + row) * HH + lane] = acc[e][0] + mgv;
        baseW[((size_t)1 * 4096 + row) * HH + lane] = acc[e][1];
        baseW[((size_t)2 * 4096 + row) * HH + lane] = acc[e][2];
    }
}

// prepH: t = 1..15 only (zfull[t-1] = baseW + hint-dot; t=0 uses baseW direct).
// 7680 blocks (15 t x 512 tiles) x 256 thr.
__global__ __launch_bounds__(256) void prepH(
    const float* __restrict__ baseW, const float* __restrict__ WhW,
    const float* __restrict__ hints, float* __restrict__ zfull) {
    const int tid = threadIdx.x;
    const int lane = tid & 127;
    const int grp = tid >> 7;
    const int bid = blockIdx.x;
    const int t = 1 + (bid >> 9);
    const int bl = bid & 511;
    const int tile = (bl & 7) * 64 + (bl >> 3);
    const int row0 = tile * 8 + grp * 4;
    const size_t zo = (size_t)(t - 1) * 3 * 4096 * HH;

#pragma unroll
    for (int e = 0; e < 4; ++e) {
        const int row = row0 + e;
        float s0 = baseW[((size_t)0 * 4096 + row) * HH + lane];
        float s1 = baseW[((size_t)1 * 4096 + row) * HH + lane];
        float s2 = baseW[((size_t)2 * 4096 + row) * HH + lane];
        const float* __restrict__ hr =
            hints + ((size_t)(t - 1) * BB * NN + row) * FH;
#pragma unroll
        for (int f = 0; f < FH; ++f) {
            const float hf = hr[f];
            s0 = fmaf(hf, WhW[(0 * FH + f) * HH + lane], s0);
            s1 = fmaf(hf, WhW[(1 * FH + f) * HH + lane], s1);
            s2 = fmaf(hf, WhW[(2 * FH + f) * HH + lane], s2);
        }
        zfull[zo + ((size_t)0 * 4096 + row) * HH + lane] = s0;
        zfull[zo + ((size_t)1 * 4096 + row) * HH + lane] = s1;
        zfull[zo + ((size_t)2 * 4096 + row) * HH + lane] = s2;
    }
}

// K1 (exact R18/R22 version): 512 blocks x 256 thr, Wj b128 coalesced weights.
__global__ __launch_bounds__(256) void k1_gemm(
    const float* __restrict__ hid, const float* __restrict__ Wj,
    const float* __restrict__ zp,
    float* __restrict__ m1n, float* __restrict__ m2n, float* __restrict__ o1n) {
    __shared__ float zs[8][HH];
    const int tid = threadIdx.x;
    const int lane = tid & 127;
    const int grp = tid >> 7;
    const int g4 = grp * 4;
    const int bid = blockIdx.x;
    const int tile = (bid & 7) * 64 + (bid >> 3);
    const int row0 = tile * 8;

#pragma unroll
    for (int rr = 0; rr < 4; ++rr)
        zs[g4 + rr][lane] = hid[(size_t)(row0 + g4 + rr) * HH + lane];
    __syncthreads();

    float acc[4][3];
#pragma unroll
    for (int r = 0; r < 4; ++r) { acc[r][0] = 0.f; acc[r][1] = 0.f; acc[r][2] = 0.f; }

#pragma unroll 2
    for (int kk = 0; kk < 32; ++kk) {
        const float* __restrict__ wb = Wj + (size_t)kk * 1536 + lane * 4;
        float4 w1 = *(const float4*)(wb);
        float4 w2 = *(const float4*)(wb + 512);
        float4 w3 = *(const float4*)(wb + 1024);
        float4 z0 = *(const float4*)&zs[g4 + 0][kk * 4];
        float4 z1 = *(const float4*)&zs[g4 + 1][kk * 4];
        float4 z2 = *(const float4*)&zs[g4 + 2][kk * 4];
        float4 z3 = *(const float4*)&zs[g4 + 3][kk * 4];
#define K1R(ZR, R)                                                      \
        acc[R][0] = fmaf(ZR.x, w1.x, acc[R][0]);                        \
        acc[R][0] = fmaf(ZR.y, w1.y, acc[R][0]);                        \
        acc[R][0] = fmaf(ZR.z, w1.z, acc[R][0]);                        \
        acc[R][0] = fmaf(ZR.w, w1.w, acc[R][0]);                        \
        acc[R][1] = fmaf(ZR.x, w2.x, acc[R][1]);                        \
        acc[R][1] = fmaf(ZR.y, w2.y, acc[R][1]);                        \
        acc[R][1] = fmaf(ZR.z, w2.z, acc[R][1]);                        \
        acc[R][1] = fmaf(ZR.w, w2.w, acc[R][1]);                        \
        acc[R][2] = fmaf(ZR.x, w3.x, acc[R][2]);                        \
        acc[R][2] = fmaf(ZR.y, w3.y, acc[R][2]);                        \
        acc[R][2] = fmaf(ZR.z, w3.z, acc[R][2]);                        \
        acc[R][2] = fmaf(ZR.w, w3.w, acc[R][2]);
        K1R(z0, 0) K1R(z1, 1) K1R(z2, 2) K1R(z3, 3)
#undef K1R
    }

#pragma unroll
    for (int e = 0; e < 4; ++e) {
        const int row = row0 + g4 + e;
        m1n[(size_t)row * HH + lane] =
            acc[e][0] + zp[((size_t)0 * 4096 + row) * HH + lane];
        m2n[(size_t)row * HH + lane] =
            acc[e][1] + zp[((size_t)1 * 4096 + row) * HH + lane];
        o1n[(size_t)row * HH + lane] =
            acc[e][2] + zp[((size_t)2 * 4096 + row) * HH + lane];
    }
}

// K2 (exact R22 version: 128 thr, int4 jl, b128 interleaved Wo2j/Wdnj/Wdej).
__global__ __launch_bounds__(HH) void k2_max(
    const uint4* __restrict__ eg16, const int* __restrict__ jl,
    const int* __restrict__ cnt, const float* __restrict__ We,
    const float* __restrict__ m1p, const float* __restrict__ m2,
    const float* __restrict__ o1, const float* __restrict__ Wo2j,
    const float* __restrict__ Wdnj, const float* __restrict__ Wdej,
    float* __restrict__ hid, float* __restrict__ out, int t, int last) {
    __shared__ float agg_lds[HH];
    __shared__ float hnew_lds[HH];
    const int h = threadIdx.x;
    const int bid = blockIdx.x;
    const int bi = (bid & 7) * 512 + (bid >> 3);
    const int b = bi >> 7;

    const float we0 = We[0 * HH + h], we1 = We[1 * HH + h];
    const float we2 = We[2 * HH + h], we3 = We[3 * HH + h];
    const float we4 = We[4 * HH + h], we5 = We[5 * HH + h];
    const float we6 = We[6 * HH + h], we7 = We[7 * HH + h];

    const uint4* __restrict__ egp = eg16 + (size_t)bi * NN;
    const int* __restrict__ jlb = jl + bi * NN;
    const float* __restrict__ m2b = m2 + (size_t)b * NN * HH;
    const int cp = cnt[bi];
    const float m1v = m1p[(size_t)bi * HH + h];
    const float o1v = o1[(size_t)bi * HH + h];

    float M = -3e38f;
    const int nch = cp >> 3;
    for (int ch = 0; ch < nch; ++ch) {
        const int k0 = ch * 8;
        uint4 raw[8];
        float mv[8];
        int4 ja = *(const int4*)&jlb[k0];
        int4 jb = *(const int4*)&jlb[k0 + 4];
        const int jj[8] = {ja.x, ja.y, ja.z, ja.w, jb.x, jb.y, jb.z, jb.w};
#pragma unroll
        for (int s = 0; s < 8; ++s) raw[s] = egp[k0 + s];
#pragma unroll
        for (int s = 0; s < 8; ++s) mv[s] = m2b[jj[s] * HH + h];
#pragma unroll
        for (int s = 0; s < 8; ++s) {
            uint32_t x = raw[s].x, y = raw[s].y, z = raw[s].z, w = raw[s].w;
            float e = __uint_as_float(x << 16) * we0;
            e = fmaf(__uint_as_float(x & 0xffff0000u), we1, e);
            e = fmaf(__uint_as_float(y << 16), we2, e);
            e = fmaf(__uint_as_float(y & 0xffff0000u), we3, e);
            e = fmaf(__uint_as_float(z << 16), we4, e);
            e = fmaf(__uint_as_float(z & 0xffff0000u), we5, e);
            e = fmaf(__uint_as_float(w << 16), we6, e);
            e = fmaf(__uint_as_float(w & 0xffff0000u), we7, e);
            M = fmaxf(M, e + mv[s]);
        }
    }
    float agg = (cp > 0) ? fmaxf(m1v + M, 0.f) : -1e9f;
    agg_lds[h] = agg;
    __syncthreads();

    float acc = o1v;
    const float4* a4 = (const float4*)agg_lds;
#pragma unroll 8
    for (int kk = 0; kk < 32; ++kk) {
        float4 a = a4[kk];
        float4 w = *(const float4*)&Wo2j[(kk * HH + h) * 4];
        acc = fmaf(a.x, w.x, acc);
        acc = fmaf(a.y, w.y, acc);
        acc = fmaf(a.z, w.z, acc);
        acc = fmaf(a.w, w.w, acc);
    }
    float hv = fmaxf(acc, 0.f);
    hid[(size_t)bi * HH + h] = hv;

    if (last) {
        hnew_lds[h] = hv;
        __syncthreads();
        if (h < DEC) {
            float a = 0.f, e2 = 0.f;
            const float4* h4p = (const float4*)hnew_lds;
#pragma unroll 8
            for (int kk = 0; kk < 32; ++kk) {
                float4 hv4 = h4p[kk];
                float4 av4 = a4[kk];
                float4 wn = *(const float4*)&Wdnj[(kk * DEC + h) * 4];
                float4 wd = *(const float4*)&Wdej[(kk * DEC + h) * 4];
                a = fmaf(hv4.x, wn.x, a);
                a = fmaf(hv4.y, wn.y, a);
                a = fmaf(hv4.z, wn.z, a);
                a = fmaf(hv4.w, wn.w, a);
                e2 = fmaf(av4.x, wd.x, e2);
                e2 = fmaf(av4.y, wd.y, e2);
                e2 = fmaf(av4.z, wd.z, e2);
                e2 = fmaf(av4.w, wd.w, e2);
            }
            out[(((size_t)t * BB + b) * NN + (bi & 127)) * DEC + h] = a + e2;
        }
    }
}

extern "C" void kernel_launch(void* const* d_in, const int* in_sizes, int n_in,
                              void* d_out, int out_size, void* d_ws, size_t ws_size,
                              hipStream_t stream) {
    const float* node = (const float*)d_in[0];
    const float* edge = (const float*)d_in[1];
    const float* graph = (const float*)d_in[2];
    const float* hints = (const float*)d_in[3];
    const int* adj = (const int*)d_in[4];
    const float* Wn = (const float*)d_in[5];
    const float* Wh = (const float*)d_in[6];
    const float* Wee = (const float*)d_in[7];
    const float* Wg = (const float*)d_in[8];
    const float* Wm1 = (const float*)d_in[9];
    const float* Wm2 = (const float*)d_in[10];
    const float* Wme = (const float*)d_in[11];
    const float* Wmg = (const float*)d_in[12];
    const float* Wo1 = (const float*)d_in[13];
    const float* Wo2 = (const float*)d_in[14];
    const float* Wdn = (const float*)d_in[15];
    const float* Wde = (const float*)d_in[16];

    float* ws = (float*)d_ws;
    float* We = ws + 524288;
    float* mg = ws + 525312;
    uint4* eg16 = (uint4*)(ws + 529408);
    int* jl = (int*)(ws + 2626560);
    int* cnt = (int*)(ws + 3150848);
    float* WhW = ws + 3154944;
    float* baseW = ws + 3161088;
    float* m1p = ws + 4733952;
    float* m2 = ws + 5258240;
    float* o1 = ws + 5782528;
    float* hid = ws + 6306816;
    float* Wj = ws + 6831104;
    float* zfull = ws + 6880256;
    float* Wo2j = ws + 32046080;
    float* Wdnj = ws + 32062464;
    float* Wdej = ws + 32070656;
    float* out = (float*)d_out;

    const size_t MS = (size_t)4096 * HH;

    prep2<<<BB + FE, HH, 0, stream>>>(graph, Wg, Wmg, Wee, Wme, mg, We);
    prep3<<<BB * NN, HH, 0, stream>>>(edge, adj, eg16, jl, cnt);
    prepWJO<<<368, 256, 0, stream>>>(Wh, Wm1, Wm2, Wo1, Wo2, Wdn, Wde,
                                     WhW, Wj, Wo2j, Wdnj, Wdej);
    prepB<<<512, 512, 0, stream>>>(node, Wn, Wm1, Wm2, Wo1, mg, baseW);
    prepH<<<7680, 256, 0, stream>>>(baseW, WhW, hints, zfull);

    for (int r = 0; r < 48; ++r) {
        const int t = r / 3;
        const int last = ((r % 3) == 2) ? 1 : 0;
        const float* zt = (t == 0) ? baseW : zfull + (size_t)(t - 1) * 3 * MS;
        const float *m1c, *m2c, *o1c;
        if (r == 0) {
            m1c = zt; m2c = zt + MS; o1c = zt + 2 * MS;
        } else {
            k1_gemm<<<512, 256, 0, stream>>>(hid, Wj, zt, m1p, m2, o1);
            m1c = m1p; m2c = m2; o1c = o1;
        }
        k2_max<<<BB * NN, HH, 0, stream>>>(eg16, jl, cnt, We, m1c, m2c, o1c,
                                           Wo2j, Wdnj, Wdej, hid, out, t, last);
    }
}

// Round 25
// 1770.002 us; speedup vs baseline: 1.0516x; 1.0180x over previous
//
#include <hip/hip_runtime.h>
#include <hip/hip_bf16.h>
#include <stdint.h>

#define BB 32
#define NN 128
#define TT 16
#define FN 16
#define FE 8
#define FG 8
#define FH 16
#define HH 128
#define DEC 64

// ws layout (floats):
// We        @524288   [1024]
// mg        @525312   [4096]
// eg16      @529408   [2097152]
// jl (int)  @2626560  [524288]
// cnt (int) @3150848  [4096]
// WhW       @3154944  [6144]
// baseW     @3161088  [1572864]   ([3][4096][128], m1 slice includes +mg)
// m1p       @4733952  [524288]
// m2        @5258240  [524288]
// o1        @5782528  [524288]
// hid       @6306816  [524288]
// Wj        @6831104  [49152]     ([32 kk][3 m][128 h][4 u])
// zfull     @6880256  [25165824]  ([16 t][3 m][4096 row][128 h])
// Wo2j      @32046080 [16384]
// Wdnj      @32062464 [8192]
// Wdej      @32070656 [8192]
// end 32078848 floats = 128.3 MB (ws = 256 MB)

__global__ __launch_bounds__(HH) void prep2(const float* __restrict__ graph,
                                            const float* __restrict__ Wg,
                                            const float* __restrict__ Wmg,
                                            const float* __restrict__ Wee,
                                            const float* __restrict__ Wme,
                                            float* __restrict__ mg,
                                            float* __restrict__ We) {
    int h = threadIdx.x;
    if (blockIdx.x < BB) {
        int b = blockIdx.x;
        __shared__ float gf[HH];
        float acc = 0.f;
#pragma unroll
        for (int f = 0; f < FG; ++f) acc += graph[b * FG + f] * Wg[f * HH + h];
        gf[h] = acc;
        __syncthreads();
        float a2 = 0.f;
#pragma unroll 16
        for (int k = 0; k < HH; ++k) a2 += gf[k] * Wmg[k * HH + h];
        mg[b * HH + h] = a2;
    } else {
        int f = blockIdx.x - BB;
        float acc = 0.f;
#pragma unroll 16
        for (int k = 0; k < HH; ++k) acc += Wee[f * HH + k] * Wme[k * HH + h];
        We[f * HH + h] = acc;
    }
}

__device__ __forceinline__ uint32_t bf16rne(float v) {
    uint32_t b = __float_as_uint(v);
    return (b + 0x7fffu + ((b >> 16) & 1u)) >> 16;
}

__global__ __launch_bounds__(HH) void prep3(const float* __restrict__ edge,
                                            const int* __restrict__ adj,
                                            uint4* __restrict__ eg16,
                                            int* __restrict__ jl,
                                            int* __restrict__ cnt) {
    int bi = blockIdx.x;
    int j = threadIdx.x;
    __shared__ int w0cnt, totc, j0s;
    bool valid = adj[(size_t)bi * NN + j] > 0;
    unsigned long long mask = __ballot(valid);
    int lane = j & 63;
    int wave = j >> 6;
    int prefix = __popcll(mask & ((1ull << lane) - 1ull));
    int wcount = __popcll(mask);
    if (wave == 0 && lane == 0) w0cnt = wcount;
    __syncthreads();
    int base = (wave == 1) ? w0cnt : 0;
    if (wave == 1 && lane == 0) totc = w0cnt + wcount;
    int pos = base + prefix;
    if (valid && pos == 0) j0s = j;
    __syncthreads();
    int c = totc;
    int cpad = (c + 7) & ~7;
    if (j == 0) cnt[bi] = cpad;

    if (valid) {
        jl[bi * NN + pos] = j;
        const float* src = edge + ((size_t)bi * NN + j) * FE;
        uint4 r;
        r.x = bf16rne(src[0]) | (bf16rne(src[1]) << 16);
        r.y = bf16rne(src[2]) | (bf16rne(src[3]) << 16);
        r.z = bf16rne(src[4]) | (bf16rne(src[5]) << 16);
        r.w = bf16rne(src[6]) | (bf16rne(src[7]) << 16);
        eg16[(size_t)bi * NN + pos] = r;
    }
    if (c > 0 && j >= c && j < cpad) {
        int j0 = j0s;
        jl[bi * NN + j] = j0;
        const float* src = edge + ((size_t)bi * NN + j0) * FE;
        uint4 r;
        r.x = bf16rne(src[0]) | (bf16rne(src[1]) << 16);
        r.y = bf16rne(src[2]) | (bf16rne(src[3]) << 16);
        r.z = bf16rne(src[4]) | (bf16rne(src[5]) << 16);
        r.w = bf16rne(src[6]) | (bf16rne(src[7]) << 16);
        eg16[(size_t)bi * NN + j] = r;
    }
}

// Merged prepW + prepJ + prepO. Grid = 368 blocks x 256 thr.
__global__ __launch_bounds__(256) void prepWJO(
    const float* __restrict__ Wh, const float* __restrict__ Wm1,
    const float* __restrict__ Wm2, const float* __restrict__ Wo1,
    const float* __restrict__ Wo2, const float* __restrict__ Wdn,
    const float* __restrict__ Wde,
    float* __restrict__ WhW, float* __restrict__ Wj,
    float* __restrict__ Wo2j, float* __restrict__ Wdnj,
    float* __restrict__ Wdej) {
    const int bid = blockIdx.x;
    const int tid = threadIdx.x;
    if (bid < 48) {
        if (tid < HH) {
            const int h = tid;
            const int m = bid >> 4;
            const int f = bid & 15;
            const float* __restrict__ W = (m == 0) ? Wm1 : (m == 1) ? Wm2 : Wo1;
            float acc = 0.f;
#pragma unroll 16
            for (int k = 0; k < HH; ++k)
                acc = fmaf(Wh[f * HH + k], W[k * HH + h], acc);
            WhW[(m * FH + f) * HH + h] = acc;
        }
    } else if (bid < 240) {
        int idx = (bid - 48) * 256 + tid;   // 0..49151
        int kk = idx / 1536;
        int rem = idx - kk * 1536;
        int m = rem >> 9;
        int r2 = rem & 511;
        int h = r2 >> 2;
        int u = r2 & 3;
        const float* __restrict__ W = (m == 0) ? Wm1 : (m == 1) ? Wm2 : Wo1;
        Wj[idx] = W[(HH + kk * 4 + u) * HH + h];
    } else {
        int idx = (bid - 240) * 256 + tid;  // 0..32767
        if (idx < 16384) {
            int kk = idx >> 9;
            int h = (idx >> 2) & 127;
            int u = idx & 3;
            Wo2j[idx] = Wo2[(kk * 4 + u) * HH + h];
        } else {
            int i2 = idx - 16384;
            int which = i2 >> 13;
            int j2 = i2 & 8191;
            int kk = j2 >> 8;
            int hh = (j2 >> 2) & 63;
            int u = j2 & 3;
            if (which == 0)
                Wdnj[j2] = Wdn[(kk * 4 + u) * DEC + hh];
            else
                Wdej[j2] = Wde[(kk * 4 + u) * DEC + hh];
        }
    }
}

// baseW[m][row][h] = (node[row] @ Wn) @ Wm[:128] (+mg for m=0).
__global__ __launch_bounds__(512, 4) void prepB(
    const float* __restrict__ node, const float* __restrict__ Wn,
    const float* __restrict__ Wm1, const float* __restrict__ Wm2,
    const float* __restrict__ Wo1, const float* __restrict__ mg,
    float* __restrict__ baseW) {
    __shared__ float zs[8][HH];
    const int tid = threadIdx.x;
    const int lane = tid & 127;
    const int grp = tid >> 7;
    const int bid = blockIdx.x;
    const int tile = (bid & 7) * 64 + (bid >> 3);
    const int row0 = tile * 8;
    const int rg0 = grp * 2, rg1 = rg0 + 1;

    {
        float a0 = 0.f, a1 = 0.f;
        const float* __restrict__ n0 = node + (size_t)(row0 + rg0) * FN;
        const float* __restrict__ n1 = node + (size_t)(row0 + rg1) * FN;
#pragma unroll
        for (int f = 0; f < FN; ++f) {
            const float w = Wn[f * HH + lane];
            a0 += n0[f] * w;
            a1 += n1[f] * w;
        }
        zs[rg0][lane] = a0;
        zs[rg1][lane] = a1;
    }
    __syncthreads();

    float acc[2][3];
#pragma unroll
    for (int e = 0; e < 2; ++e) { acc[e][0] = 0.f; acc[e][1] = 0.f; acc[e][2] = 0.f; }

#pragma unroll 4
    for (int kk = 0; kk < 32; ++kk) {
        const int k0 = kk * 4;
        float4 z0 = *(const float4*)&zs[rg0][k0];
        float4 z1 = *(const float4*)&zs[rg1][k0];
#define PBU(COMP, KO)                                                   \
        {                                                               \
            const float w1 = Wm1[(k0 + KO) * HH + lane];                \
            const float w2 = Wm2[(k0 + KO) * HH + lane];                \
            const float w3 = Wo1[(k0 + KO) * HH + lane];                \
            acc[0][0] = fmaf(z0.COMP, w1, acc[0][0]);                   \
            acc[1][0] = fmaf(z1.COMP, w1, acc[1][0]);                   \
            acc[0][1] = fmaf(z0.COMP, w2, acc[0][1]);                   \
            acc[1][1] = fmaf(z1.COMP, w2, acc[1][1]);                   \
            acc[0][2] = fmaf(z0.COMP, w3, acc[0][2]);                   \
            acc[1][2] = fmaf(z1.COMP, w3, acc[1][2]);                   \
        }
        PBU(x, 0) PBU(y, 1) PBU(z, 2) PBU(w, 3)
#undef PBU
    }

#pragma unroll
    for (int e = 0; e < 2; ++e) {
        const int row = row0 + grp * 2 + e;
        const float mgv = mg[(row >> 7) * HH + lane];
        baseW[((size_t)0 * 4096 + row) * HH + lane] = acc[e][0] + mgv;
        baseW[((size_t)1 * 4096 + row) * HH + lane] = acc[e][1];
        baseW[((size_t)2 * 4096 + row) * HH + lane] = acc[e][2];
    }
}

// prepH (exact R22 version): 8192 blocks (16 t x 512 tiles) x 256 thr.
__global__ __launch_bounds__(256) void prepH(
    const float* __restrict__ baseW, const float* __restrict__ WhW,
    const float* __restrict__ hints, float* __restrict__ zfull) {
    const int tid = threadIdx.x;
    const int lane = tid & 127;
    const int grp = tid >> 7;
    const int bid = blockIdx.x;
    const int t = bid >> 9;
    const int bl = bid & 511;
    const int tile = (bl & 7) * 64 + (bl >> 3);
    const int row0 = tile * 8 + grp * 4;
    const size_t zo = (size_t)t * 3 * 4096 * HH;

#pragma unroll
    for (int e = 0; e < 4; ++e) {
        const int row = row0 + e;
        float s0 = baseW[((size_t)0 * 4096 + row) * HH + lane];
        float s1 = baseW[((size_t)1 * 4096 + row) * HH + lane];
        float s2 = baseW[((size_t)2 * 4096 + row) * HH + lane];
        if (t > 0) {
            const float* __restrict__ hr =
                hints + ((size_t)(t - 1) * BB * NN + row) * FH;
#pragma unroll
            for (int f = 0; f < FH; ++f) {
                const float hf = hr[f];
                s0 = fmaf(hf, WhW[(0 * FH + f) * HH + lane], s0);
                s1 = fmaf(hf, WhW[(1 * FH + f) * HH + lane], s1);
                s2 = fmaf(hf, WhW[(2 * FH + f) * HH + lane], s2);
            }
        }
        zfull[zo + ((size_t)0 * 4096 + row) * HH + lane] = s0;
        zfull[zo + ((size_t)1 * 4096 + row) * HH + lane] = s1;
        zfull[zo + ((size_t)2 * 4096 + row) * HH + lane] = s2;
    }
}

// K1 (exact R18/R22 version): 512 blocks x 256 thr, Wj b128 coalesced weights.
__global__ __launch_bounds__(256) void k1_gemm(
    const float* __restrict__ hid, const float* __restrict__ Wj,
    const float* __restrict__ zp,
    float* __restrict__ m1n, float* __restrict__ m2n, float* __restrict__ o1n) {
    __shared__ float zs[8][HH];
    const int tid = threadIdx.x;
    const int lane = tid & 127;
    const int grp = tid >> 7;
    const int g4 = grp * 4;
    const int bid = blockIdx.x;
    const int tile = (bid & 7) * 64 + (bid >> 3);
    const int row0 = tile * 8;

#pragma unroll
    for (int rr = 0; rr < 4; ++rr)
        zs[g4 + rr][lane] = hid[(size_t)(row0 + g4 + rr) * HH + lane];
    __syncthreads();

    float acc[4][3];
#pragma unroll
    for (int r = 0; r < 4; ++r) { acc[r][0] = 0.f; acc[r][1] = 0.f; acc[r][2] = 0.f; }

#pragma unroll 2
    for (int kk = 0; kk < 32; ++kk) {
        const float* __restrict__ wb = Wj + (size_t)kk * 1536 + lane * 4;
        float4 w1 = *(const float4*)(wb);
        float4 w2 = *(const float4*)(wb + 512);
        float4 w3 = *(const float4*)(wb + 1024);
        float4 z0 = *(const float4*)&zs[g4 + 0][kk * 4];
        float4 z1 = *(const float4*)&zs[g4 + 1][kk * 4];
        float4 z2 = *(const float4*)&zs[g4 + 2][kk * 4];
        float4 z3 = *(const float4*)&zs[g4 + 3][kk * 4];
#define K1R(ZR, R)                                                      \
        acc[R][0] = fmaf(ZR.x, w1.x, acc[R][0]);                        \
        acc[R][0] = fmaf(ZR.y, w1.y, acc[R][0]);                        \
        acc[R][0] = fmaf(ZR.z, w1.z, acc[R][0]);                        \
        acc[R][0] = fmaf(ZR.w, w1.w, acc[R][0]);                        \
        acc[R][1] = fmaf(ZR.x, w2.x, acc[R][1]);                        \
        acc[R][1] = fmaf(ZR.y, w2.y, acc[R][1]);                        \
        acc[R][1] = fmaf(ZR.z, w2.z, acc[R][1]);                        \
        acc[R][1] = fmaf(ZR.w, w2.w, acc[R][1]);                        \
        acc[R][2] = fmaf(ZR.x, w3.x, acc[R][2]);                        \
        acc[R][2] = fmaf(ZR.y, w3.y, acc[R][2]);                        \
        acc[R][2] = fmaf(ZR.z, w3.z, acc[R][2]);                        \
        acc[R][2] = fmaf(ZR.w, w3.w, acc[R][2]);
        K1R(z0, 0) K1R(z1, 1) K1R(z2, 2) K1R(z3, 3)
#undef K1R
    }

#pragma unroll
    for (int e = 0; e < 4; ++e) {
        const int row = row0 + g4 + e;
        m1n[(size_t)row * HH + lane] =
            acc[e][0] + zp[((size_t)0 * 4096 + row) * HH + lane];
        m2n[(size_t)row * HH + lane] =
            acc[e][1] + zp[((size_t)1 * 4096 + row) * HH + lane];
        o1n[(size_t)row * HH + lane] =
            acc[e][2] + zp[((size_t)2 * 4096 + row) * HH + lane];
    }
}

// K2 (exact R22 version: 128 thr, int4 jl, b128 interleaved Wo2j/Wdnj/Wdej).
__global__ __launch_bounds__(HH) void k2_max(
    const uint4* __restrict__ eg16, const int* __restrict__ jl,
    const int* __restrict__ cnt, const float* __restrict__ We,
    const float* __restrict__ m1p, const float* __restrict__ m2,
    const float* __restrict__ o1, const float* __restrict__ Wo2j,
    const float* __restrict__ Wdnj, const float* __restrict__ Wdej,
    float* __restrict__ hid, float* __restrict__ out, int t, int last) {
    __shared__ float agg_lds[HH];
    __shared__ float hnew_lds[HH];
    const int h = threadIdx.x;
    const int bid = blockIdx.x;
    const int bi = (bid & 7) * 512 + (bid >> 3);
    const int b = bi >> 7;

    const float we0 = We[0 * HH + h], we1 = We[1 * HH + h];
    const float we2 = We[2 * HH + h], we3 = We[3 * HH + h];
    const float we4 = We[4 * HH + h], we5 = We[5 * HH + h];
    const float we6 = We[6 * HH + h], we7 = We[7 * HH + h];

    const uint4* __restrict__ egp = eg16 + (size_t)bi * NN;
    const int* __restrict__ jlb = jl + bi * NN;
    const float* __restrict__ m2b = m2 + (size_t)b * NN * HH;
    const int cp = cnt[bi];
    const float m1v = m1p[(size_t)bi * HH + h];
    const float o1v = o1[(size_t)bi * HH + h];

    float M = -3e38f;
    const int nch = cp >> 3;
    for (int ch = 0; ch < nch; ++ch) {
        const int k0 = ch * 8;
        uint4 raw[8];
        float mv[8];
        int4 ja = *(const int4*)&jlb[k0];
        int4 jb = *(const int4*)&jlb[k0 + 4];
        const int jj[8] = {ja.x, ja.y, ja.z, ja.w, jb.x, jb.y, jb.z, jb.w};
#pragma unroll
        for (int s = 0; s < 8; ++s) raw[s] = egp[k0 + s];
#pragma unroll
        for (int s = 0; s < 8; ++s) mv[s] = m2b[jj[s] * HH + h];
#pragma unroll
        for (int s = 0; s < 8; ++s) {
            uint32_t x = raw[s].x, y = raw[s].y, z = raw[s].z, w = raw[s].w;
            float e = __uint_as_float(x << 16) * we0;
            e = fmaf(__uint_as_float(x & 0xffff0000u), we1, e);
            e = fmaf(__uint_as_float(y << 16), we2, e);
            e = fmaf(__uint_as_float(y & 0xffff0000u), we3, e);
            e = fmaf(__uint_as_float(z << 16), we4, e);
            e = fmaf(__uint_as_float(z & 0xffff0000u), we5, e);
            e = fmaf(__uint_as_float(w << 16), we6, e);
            e = fmaf(__uint_as_float(w & 0xffff0000u), we7, e);
            M = fmaxf(M, e + mv[s]);
        }
    }
    float agg = (cp > 0) ? fmaxf(m1v + M, 0.f) : -1e9f;
    agg_lds[h] = agg;
    __syncthreads();

    float acc = o1v;
    const float4* a4 = (const float4*)agg_lds;
#pragma unroll 8
    for (int kk = 0; kk < 32; ++kk) {
        float4 a = a4[kk];
        float4 w = *(const float4*)&Wo2j[(kk * HH + h) * 4];
        acc = fmaf(a.x, w.x, acc);
        acc = fmaf(a.y, w.y, acc);
        acc = fmaf(a.z, w.z, acc);
        acc = fmaf(a.w, w.w, acc);
    }
    float hv = fmaxf(acc, 0.f);
    hid[(size_t)bi * HH + h] = hv;

    if (last) {
        hnew_lds[h] = hv;
        __syncthreads();
        if (h < DEC) {
            float a = 0.f, e2 = 0.f;
            const float4* h4p = (const float4*)hnew_lds;
#pragma unroll 8
            for (int kk = 0; kk < 32; ++kk) {
                float4 hv4 = h4p[kk];
                float4 av4 = a4[kk];
                float4 wn = *(const float4*)&Wdnj[(kk * DEC + h) * 4];
                float4 wd = *(const float4*)&Wdej[(kk * DEC + h) * 4];
                a = fmaf(hv4.x, wn.x, a);
                a = fmaf(hv4.y, wn.y, a);
                a = fmaf(hv4.z, wn.z, a);
                a = fmaf(hv4.w, wn.w, a);
                e2 = fmaf(av4.x, wd.x, e2);
                e2 = fmaf(av4.y, wd.y, e2);
                e2 = fmaf(av4.z, wd.z, e2);
                e2 = fmaf(av4.w, wd.w, e2);
            }
            out[(((size_t)t * BB + b) * NN + (bi & 127)) * DEC + h] = a + e2;
        }
    }
}

extern "C" void kernel_launch(void* const* d_in, const int* in_sizes, int n_in,
                              void* d_out, int out_size, void* d_ws, size_t ws_size,
                              hipStream_t stream) {
    const float* node = (const float*)d_in[0];
    const float* edge = (const float*)d_in[1];
    const float* graph = (const float*)d_in[2];
    const float* hints = (const float*)d_in[3];
    const int* adj = (const int*)d_in[4];
    const float* Wn = (const float*)d_in[5];
    const float* Wh = (const float*)d_in[6];
    const float* Wee = (const float*)d_in[7];
    const float* Wg = (const float*)d_in[8];
    const float* Wm1 = (const float*)d_in[9];
    const float* Wm2 = (const float*)d_in[10];
    const float* Wme = (const float*)d_in[11];
    const float* Wmg = (const float*)d_in[12];
    const float* Wo1 = (const float*)d_in[13];
    const float* Wo2 = (const float*)d_in[14];
    const float* Wdn = (const float*)d_in[15];
    const float* Wde = (const float*)d_in[16];

    float* ws = (float*)d_ws;
    float* We = ws + 524288;
    float* mg = ws + 525312;
    uint4* eg16 = (uint4*)(ws + 529408);
    int* jl = (int*)(ws + 2626560);
    int* cnt = (int*)(ws + 3150848);
    float* WhW = ws + 3154944;
    float* baseW = ws + 3161088;
    float* m1p = ws + 4733952;
    float* m2 = ws + 5258240;
    float* o1 = ws + 5782528;
    float* hid = ws + 6306816;
    float* Wj = ws + 6831104;
    float* zfull = ws + 6880256;
    float* Wo2j = ws + 32046080;
    float* Wdnj = ws + 32062464;
    float* Wdej = ws + 32070656;
    float* out = (float*)d_out;

    const size_t MS = (size_t)4096 * HH;

    prep2<<<BB + FE, HH, 0, stream>>>(graph, Wg, Wmg, Wee, Wme, mg, We);
    prep3<<<BB * NN, HH, 0, stream>>>(edge, adj, eg16, jl, cnt);
    prepWJO<<<368, 256, 0, stream>>>(Wh, Wm1, Wm2, Wo1, Wo2, Wdn, Wde,
                                     WhW, Wj, Wo2j, Wdnj, Wdej);
    prepB<<<512, 512, 0, stream>>>(node, Wn, Wm1, Wm2, Wo1, mg, baseW);
    prepH<<<8192, 256, 0, stream>>>(baseW, WhW, hints, zfull);

    for (int r = 0; r < 48; ++r) {
        const int t = r / 3;
        const int last = ((r % 3) == 2) ? 1 : 0;
        const float* zt = zfull + (size_t)t * 3 * MS;
        const float *m1c, *m2c, *o1c;
        if (r == 0) {
            m1c = zt; m2c = zt + MS; o1c = zt + 2 * MS;
        } else {
            k1_gemm<<<512, 256, 0, stream>>>(hid, Wj, zt, m1p, m2, o1);
            m1c = m1p; m2c = m2; o1c = o1;
        }
        k2_max<<<BB * NN, HH, 0, stream>>>(eg16, jl, cnt, We, m1c, m2c, o1c,
                                           Wo2j, Wdnj, Wdej, hid, out, t, last);
    }
}